// Round 8
// baseline (371.860 us; speedup 1.0000x reference)
//
#include <hip/hip_runtime.h>

#define OUT_DIM 4096
#define DPC     16
#define NCOL    65536    // OUT_DIM * DPC
#define BATCH   512
#define TPB     256
#define NBLK    ((BATCH * OUT_DIM) / TPB)   // 8192 blocks, 1 thread = 1 window

typedef float nvec4 __attribute__((ext_vector_type(4)));   // clang-native f32x4

// Kernel 1: bf[p] = exp((1/16 - duty[p]) * bs), double-prec exp rounded to fp32
__global__ void boost_table_kernel(const float* __restrict__ duty,
                                   const float* __restrict__ bs_ptr,
                                   float* __restrict__ bf) {
    int p = blockIdx.x * blockDim.x + threadIdx.x;
    if (p < NCOL) {
        float t = (0.0625f - duty[p]) * bs_ptr[0];
        bf[p] = (float)exp((double)t);
    }
}

// Kernel 2: ALL-REGISTER, wave-free, LDS-free, barrier-free.
// Thread = window w: window floats [15w, 15w+16) covered by 5 ALIGNED f4
// (20 floats, shift sh = 15w & 3); boosted = x*bf compared with in-window
// predicate (cndmask chain, d ascending => first-max-wins like jnp.argmax).
// Out values x[16w..16w+15] = 4 aligned f4 (cache lines overlap the window
// lines -> L1/L2 hits). Store = 4 masked NT f4 (out never re-read).
// No barriers anywhere: every wave free-runs (the R2 regime that hit
// ~5.3 TB/s), at ~1.25x issued reads but ~1x HBM reads (L1/L2 absorb the
// 4-float overlaps). bf is 256 KiB -> L2-resident.
__global__ __launch_bounds__(256, 8) void dkw_kernel(const float* __restrict__ x,
                                                     const float* __restrict__ bf,
                                                     float* __restrict__ out) {
    const int g  = blockIdx.x * TPB + threadIdx.x;  // global window id
    const int r  = g >> 12;                         // row (4096 windows/row)
    const int wr = g & 4095;                        // window within row
    const int f  = wr * 15;                         // window start float (row-local)
    const int b4 = f >> 2;                          // aligned f4 base
    const int sh = f & 3;                           // window offset in base f4
    const int o4 = wr << 2;                         // out-span f4 base (16w/4)

    const float4* __restrict__ xr = (const float4*)x + (r << 14);  // row base
    const float4* __restrict__ br = (const float4*)bf;

    // issue all x reads first (win 5 f4 + out 4 f4), then bf (L2-hot)
    const float4 xa0 = xr[b4 + 0], xa1 = xr[b4 + 1], xa2 = xr[b4 + 2],
                 xa3 = xr[b4 + 3], xa4 = xr[b4 + 4];
    const float4 xo0 = xr[o4 + 0], xo1 = xr[o4 + 1],
                 xo2 = xr[o4 + 2], xo3 = xr[o4 + 3];
    const float4 qa0 = br[b4 + 0], qa1 = br[b4 + 1], qa2 = br[b4 + 2],
                 qa3 = br[b4 + 3], qa4 = br[b4 + 4];

    float best = -__builtin_inff();
    int   bj   = 0;
    // slot d in [0,20): window index j = d - sh, valid iff 0 <= j < 16.
    // d ascending + strict '>' => first occurrence of max wins (jnp.argmax).
    #define STEP(xc, qc, d)                                        \
    {                                                              \
        const float bv = (xc) * (qc);                              \
        const int   jj = (d) - sh;                                 \
        if (((unsigned)jj < 16u) && (bv > best)) {                 \
            best = bv; bj = jj;                                    \
        }                                                          \
    }
    STEP(xa0.x, qa0.x,  0) STEP(xa0.y, qa0.y,  1) STEP(xa0.z, qa0.z,  2) STEP(xa0.w, qa0.w,  3)
    STEP(xa1.x, qa1.x,  4) STEP(xa1.y, qa1.y,  5) STEP(xa1.z, qa1.z,  6) STEP(xa1.w, qa1.w,  7)
    STEP(xa2.x, qa2.x,  8) STEP(xa2.y, qa2.y,  9) STEP(xa2.z, qa2.z, 10) STEP(xa2.w, qa2.w, 11)
    STEP(xa3.x, qa3.x, 12) STEP(xa3.y, qa3.y, 13) STEP(xa3.z, qa3.z, 14) STEP(xa3.w, qa3.w, 15)
    STEP(xa4.x, qa4.x, 16) STEP(xa4.y, qa4.y, 17) STEP(xa4.z, qa4.z, 18) STEP(xa4.w, qa4.w, 19)
    #undef STEP

    // masked NT stores: out[16w+d] = x[16w+d] * (d == bj)
    float4* __restrict__ og = (float4*)out + (r << 14) + o4;
    float4 o;
    o.x = (bj ==  0) ? xo0.x : 0.0f;  o.y = (bj ==  1) ? xo0.y : 0.0f;
    o.z = (bj ==  2) ? xo0.z : 0.0f;  o.w = (bj ==  3) ? xo0.w : 0.0f;
    __builtin_nontemporal_store(*(const nvec4*)&o, (nvec4*)&og[0]);
    o.x = (bj ==  4) ? xo1.x : 0.0f;  o.y = (bj ==  5) ? xo1.y : 0.0f;
    o.z = (bj ==  6) ? xo1.z : 0.0f;  o.w = (bj ==  7) ? xo1.w : 0.0f;
    __builtin_nontemporal_store(*(const nvec4*)&o, (nvec4*)&og[1]);
    o.x = (bj ==  8) ? xo2.x : 0.0f;  o.y = (bj ==  9) ? xo2.y : 0.0f;
    o.z = (bj == 10) ? xo2.z : 0.0f;  o.w = (bj == 11) ? xo2.w : 0.0f;
    __builtin_nontemporal_store(*(const nvec4*)&o, (nvec4*)&og[2]);
    o.x = (bj == 12) ? xo3.x : 0.0f;  o.y = (bj == 13) ? xo3.y : 0.0f;
    o.z = (bj == 14) ? xo3.z : 0.0f;  o.w = (bj == 15) ? xo3.w : 0.0f;
    __builtin_nontemporal_store(*(const nvec4*)&o, (nvec4*)&og[3]);
}

extern "C" void kernel_launch(void* const* d_in, const int* in_sizes, int n_in,
                              void* d_out, int out_size, void* d_ws, size_t ws_size,
                              hipStream_t stream) {
    const float* x    = (const float*)d_in[0];
    const float* duty = (const float*)d_in[1];
    const float* bs   = (const float*)d_in[2];
    float* out = (float*)d_out;
    float* bf  = (float*)d_ws;   // 65536 floats = 256 KiB scratch

    hipLaunchKernelGGL(boost_table_kernel, dim3(NCOL / 256), dim3(256), 0, stream,
                       duty, bs, bf);
    hipLaunchKernelGGL(dkw_kernel, dim3(NBLK), dim3(TPB), 0, stream,
                       x, bf, out);
}

// Round 9
// 259.357 us; speedup vs baseline: 1.4338x; 1.4338x over previous
//
#include <hip/hip_runtime.h>

#define OUT_DIM 4096
#define DPC     16
#define NCOL    65536    // OUT_DIM * DPC
#define BATCH   512
#define NWAVE   32768    // total 64-window chunks (2M windows / 64)
#define NF4     8388608  // total out float4s (512*65536/4)

typedef float nvec4 __attribute__((ext_vector_type(4)));   // clang-native f32x4

// Kernel 1: bf[p] = exp((1/16 - duty[p]) * bs), double-prec exp rounded to fp32
__global__ void boost_table_kernel(const float* __restrict__ duty,
                                   const float* __restrict__ bs_ptr,
                                   float* __restrict__ bf) {
    int p = blockIdx.x * blockDim.x + threadIdx.x;
    if (p < NCOL) {
        float t = (0.0625f - duty[p]) * bs_ptr[0];
        bf[p] = (float)exp((double)t);
    }
}

// K2a: winners only. R2's proven wave-independent structure (best measured),
// minus the entire out-span value path. Wave = 64 windows: stage boosted span
// (1024 floats) to private LDS, stride-15 argmax, write ONE byte per window
// (wave writes 64 consecutive bytes). Read-dominated pure stream:
// ~130 MB x + L2-hot bf in, 2 MB out. No s_barrier anywhere.
__global__ __launch_bounds__(256, 8) void winners_kernel(const float* __restrict__ x,
                                                         const float* __restrict__ bf,
                                                         unsigned char* __restrict__ sj) {
    __shared__ float sb[4][1024];   // boosted span per wave, 16 KiB

    const int lane = threadIdx.x & 63;
    const int wv   = threadIdx.x >> 6;                 // wave in block
    const int gw   = blockIdx.x * 4 + wv;              // global wave id
    const int row  = gw >> 6;                          // 64 waves per row
    const int wc   = gw & 63;                          // chunk within row
    const int rowbase = row << 16;                     // row * 65536

    const int in_off = wc * 960;                       // 16B-aligned
    const float4* __restrict__ xg = (const float4*)(x + rowbase + in_off);
    const float4* __restrict__ bg = (const float4*)(bf + in_off);
    float4* __restrict__ sb4 = (float4*)sb[wv];
    #pragma unroll
    for (int r = 0; r < 4; ++r) {
        const int i = lane + 64 * r;                   // 256 f4 = 1024 floats
        float4 a = xg[i];
        float4 b = bg[i];
        float4 p;
        p.x = a.x * b.x; p.y = a.y * b.y; p.z = a.z * b.z; p.w = a.w * b.w;
        sb4[i] = p;
    }
    asm volatile("" ::: "memory");   // same-wave DS is in-order; no HW wait

    const float* __restrict__ p = sb[wv] + lane * 15;  // 2-way bank = free
    float best = p[0];
    int   bj   = 0;
    #pragma unroll
    for (int k = 1; k < DPC; ++k) {
        float v = p[k];
        if (v > best) { best = v; bj = k; }            // strict >: first max wins
    }
    sj[(gw << 6) + lane] = (unsigned char)bj;          // 64B/wave, coalesced
}

// K2b: masked copy — the m13 float4-copy shape (proven 6.3 TB/s on this chip).
// Thread t handles 8 INDEPENDENT f4s (t + k*2^20): all loads issued up front,
// lane-consecutive reads AND stores (no R8 write-amplification). Mask from the
// 2 MB sj table (4-lane byte broadcast). x was loaded into L3 by K2a moments
// earlier -> reads should be largely L3 hits. NT stores (out never re-read).
__global__ __launch_bounds__(256, 8) void mask_kernel(const float* __restrict__ x,
                                                      const unsigned char* __restrict__ sj,
                                                      float* __restrict__ out) {
    const int t = blockIdx.x * 256 + threadIdx.x;      // 0 .. 2^20-1
    const float4* __restrict__ x4 = (const float4*)x;
    float4* __restrict__ o4 = (float4*)out;

    float4 v[8];
    int    jm[8];
    #pragma unroll
    for (int k = 0; k < 8; ++k) {
        const int j = t + (k << 20);                   // f4 index, < NF4
        v[k]  = x4[j];
        jm[k] = (int)sj[j >> 2];                       // window winner (broadcast x4)
    }
    #pragma unroll
    for (int k = 0; k < 8; ++k) {
        const int j  = t + (k << 20);
        const int j0 = (j & 3) << 2;                   // first slot of this f4
        float4 o;
        o.x = (jm[k] == j0    ) ? v[k].x : 0.0f;
        o.y = (jm[k] == j0 + 1) ? v[k].y : 0.0f;
        o.z = (jm[k] == j0 + 2) ? v[k].z : 0.0f;
        o.w = (jm[k] == j0 + 3) ? v[k].w : 0.0f;
        __builtin_nontemporal_store(*(const nvec4*)&o, (nvec4*)&o4[j]);
    }
}

// Fallback: best-known monolithic kernel (R2, 237.5 us total) if ws too small.
__global__ __launch_bounds__(256, 8) void dkw_kernel(const float* __restrict__ x,
                                                     const float* __restrict__ bf,
                                                     float* __restrict__ out) {
    __shared__ float sb[4][1024];
    __shared__ int   sj[4][64];

    const int lane = threadIdx.x & 63;
    const int wv   = threadIdx.x >> 6;
    const int gw   = blockIdx.x * 4 + wv;
    const int row  = gw >> 6;
    const int wc   = gw & 63;
    const int rowbase = row << 16;

    const int in_off = wc * 960;
    const float4* __restrict__ xg   = (const float4*)(x + rowbase + in_off);
    const float4* __restrict__ bg   = (const float4*)(bf + in_off);
    const float4* __restrict__ xo_g = (const float4*)(x + rowbase + (wc << 10));
    float4* __restrict__ sb4 = (float4*)sb[wv];
    #pragma unroll
    for (int r = 0; r < 4; ++r) {
        const int i = lane + 64 * r;
        float4 a = xg[i];
        float4 b = bg[i];
        float4 p;
        p.x = a.x * b.x; p.y = a.y * b.y; p.z = a.z * b.z; p.w = a.w * b.w;
        sb4[i] = p;
    }
    float4 xo0 = xo_g[lane];
    float4 xo1 = xo_g[lane + 64];
    float4 xo2 = xo_g[lane + 128];
    float4 xo3 = xo_g[lane + 192];
    asm volatile("" ::: "memory");

    {
        const float* __restrict__ p = sb[wv] + lane * 15;
        float best = p[0];
        int   bj   = 0;
        #pragma unroll
        for (int k = 1; k < DPC; ++k) {
            float v = p[k];
            if (v > best) { best = v; bj = k; }
        }
        sj[wv][lane] = bj;
    }
    asm volatile("" ::: "memory");

    float4* __restrict__ og = (float4*)(out + rowbase + (wc << 10));
    const float4 xoarr[4] = {xo0, xo1, xo2, xo3};
    #pragma unroll
    for (int r = 0; r < 4; ++r) {
        const int i  = lane + 64 * r;
        const int w  = i >> 2;
        const int jm = sj[wv][w];
        const float4 v = xoarr[r];
        const int j0 = (i & 3) << 2;
        float4 o;
        o.x = (j0     == jm) ? v.x : 0.0f;
        o.y = (j0 + 1 == jm) ? v.y : 0.0f;
        o.z = (j0 + 2 == jm) ? v.z : 0.0f;
        o.w = (j0 + 3 == jm) ? v.w : 0.0f;
        __builtin_nontemporal_store(*(const nvec4*)&o, (nvec4*)&og[i]);
    }
}

extern "C" void kernel_launch(void* const* d_in, const int* in_sizes, int n_in,
                              void* d_out, int out_size, void* d_ws, size_t ws_size,
                              hipStream_t stream) {
    const float* x    = (const float*)d_in[0];
    const float* duty = (const float*)d_in[1];
    const float* bs   = (const float*)d_in[2];
    float* out = (float*)d_out;
    float* bf  = (float*)d_ws;                         // 256 KiB
    unsigned char* sj = (unsigned char*)d_ws + NCOL * sizeof(float);  // 2 MiB

    hipLaunchKernelGGL(boost_table_kernel, dim3(NCOL / 256), dim3(256), 0, stream,
                       duty, bs, bf);

    if (ws_size >= NCOL * sizeof(float) + (size_t)(BATCH * OUT_DIM)) {
        hipLaunchKernelGGL(winners_kernel, dim3(NWAVE / 4), dim3(256), 0, stream,
                           x, bf, sj);
        hipLaunchKernelGGL(mask_kernel, dim3(NF4 / 8 / 256), dim3(256), 0, stream,
                           x, sj, out);
    } else {
        hipLaunchKernelGGL(dkw_kernel, dim3(NWAVE / 4), dim3(256), 0, stream,
                           x, bf, out);
    }
}

// Round 10
// 237.027 us; speedup vs baseline: 1.5688x; 1.0942x over previous
//
#include <hip/hip_runtime.h>

#define OUT_DIM 4096
#define DPC     16
#define NCOL    65536    // OUT_DIM * DPC
#define BATCH   512
#define NWAVE   32768    // total 64-window chunks (2M windows / 64)

typedef float nvec4 __attribute__((ext_vector_type(4)));   // clang-native f32x4

// Kernel 1: bf[p] = exp((1/16 - duty[p]) * bs), double-prec exp rounded to fp32
// (bit-exact vs jnp.exp; table is 256 KiB -> L2/L3-resident for kernel 2)
__global__ void boost_table_kernel(const float* __restrict__ duty,
                                   const float* __restrict__ bs_ptr,
                                   float* __restrict__ bf) {
    int p = blockIdx.x * blockDim.x + threadIdx.x;
    if (p < NCOL) {
        float t = (0.0625f - duty[p]) * bs_ptr[0];
        bf[p] = (float)exp((double)t);
    }
}

// Kernel 2: session-best structure (measured 237.5 us total; prior session's
// near-identical variant 237.2). Wave-independent free-running streaming:
// each wave64 owns 64 windows and a private LDS region, NO __syncthreads
// anywhere -> per-CU wave phases stay mixed, reads/writes interleave.
// Verdict from 9 structural probes (traffic-minimal, occupancy-maximal,
// persistent-pipelined, all-register, split): dkw is pinned at ~77 us
// (~268 MB real HBM, 2.6-3.5 TB/s effective) by harness-fill L2/L3
// writeback contention, not by anything kernel-controlled.
__global__ __launch_bounds__(256, 8) void dkw_kernel(const float* __restrict__ x,
                                                     const float* __restrict__ bf,
                                                     float* __restrict__ out) {
    __shared__ float sb[4][1024];   // boosted span per wave, 16 KiB
    __shared__ int   sj[4][64];     // winner j per window

    const int lane = threadIdx.x & 63;
    const int wv   = threadIdx.x >> 6;                 // wave in block
    const int gw   = blockIdx.x * 4 + wv;              // global wave id
    const int row  = gw >> 6;                          // 64 waves per row
    const int wc   = gw & 63;                          // chunk within row
    const int rowbase = row << 16;                     // row * 65536

    // ---- P1: stage boosted = x*bf for span [960*wc, 960*wc+1024) of row ----
    const int in_off = wc * 960;                       // 16B-aligned
    const float4* __restrict__ xg   = (const float4*)(x + rowbase + in_off);
    const float4* __restrict__ bg   = (const float4*)(bf + in_off);
    const float4* __restrict__ xo_g = (const float4*)(x + rowbase + (wc << 10));
    float4* __restrict__ sb4 = (float4*)sb[wv];
    #pragma unroll
    for (int r = 0; r < 4; ++r) {
        const int i = lane + 64 * r;                   // 256 f4 = 1024 floats
        float4 a = xg[i];
        float4 b = bg[i];
        float4 p;
        p.x = a.x * b.x; p.y = a.y * b.y; p.z = a.z * b.z; p.w = a.w * b.w;
        sb4[i] = p;
    }
    // out-span x, coalesced; consumed only in P3 -> latency hidden
    float4 xo0 = xo_g[lane];
    float4 xo1 = xo_g[lane + 64];
    float4 xo2 = xo_g[lane + 128];
    float4 xo3 = xo_g[lane + 192];
    asm volatile("" ::: "memory");   // compiler barrier; same-wave DS is in-order

    // ---- P2: lane = window wc*64+lane; argmax over LDS stride-15 ----
    {
        const float* __restrict__ p = sb[wv] + lane * 15;   // 2-way bank = free
        float best = p[0];
        int   bj   = 0;
        #pragma unroll
        for (int k = 1; k < DPC; ++k) {
            float v = p[k];
            if (v > best) { best = v; bj = k; }   // strict >: first max wins
        }
        sj[wv][lane] = bj;
    }
    asm volatile("" ::: "memory");

    // ---- P3: coalesced masked NT-store epilogue: 256 f4 = 4 KiB span ----
    float4* __restrict__ og = (float4*)(out + rowbase + (wc << 10));
    const float4 xoarr[4] = {xo0, xo1, xo2, xo3};      // const-indexed -> regs
    #pragma unroll
    for (int r = 0; r < 4; ++r) {
        const int i  = lane + 64 * r;
        const int w  = i >> 2;                // window within chunk
        const int jm = sj[wv][w];
        const float4 v = xoarr[r];
        const int j0 = (i & 3) << 2;
        float4 o;
        o.x = (j0     == jm) ? v.x : 0.0f;
        o.y = (j0 + 1 == jm) ? v.y : 0.0f;
        o.z = (j0 + 2 == jm) ? v.z : 0.0f;
        o.w = (j0 + 3 == jm) ? v.w : 0.0f;
        __builtin_nontemporal_store(*(const nvec4*)&o, (nvec4*)&og[i]);
    }
}

extern "C" void kernel_launch(void* const* d_in, const int* in_sizes, int n_in,
                              void* d_out, int out_size, void* d_ws, size_t ws_size,
                              hipStream_t stream) {
    const float* x    = (const float*)d_in[0];
    const float* duty = (const float*)d_in[1];
    const float* bs   = (const float*)d_in[2];
    float* out = (float*)d_out;
    float* bf  = (float*)d_ws;   // 65536 floats = 256 KiB scratch

    hipLaunchKernelGGL(boost_table_kernel, dim3(NCOL / 256), dim3(256), 0, stream,
                       duty, bs, bf);
    hipLaunchKernelGGL(dkw_kernel, dim3(NWAVE / 4), dim3(256), 0, stream,
                       x, bf, out);
}